// Round 4
// baseline (223.599 us; speedup 1.0000x reference)
//
#include <hip/hip_runtime.h>

// Haar DWT, mode=0 (no pad).
// in : (2,16,16,256,256) f32  -> plane pl = b*256 + pcd in [0,512), each plane 256x256
// out: (2,64,16,128,128) f32  -> flat (b*1024 + s*256 + pcd)*16384 + h2*128 + w2
//
// Per 2x2 quad (a=ev/ev, b=od/ev, c=ev/od, d=od/od), all *0.5:
//   LL = a+b+c+d ; HL = -a-b+c+d ; LH = -a+b-c+d ; HH = a-b-c+d
//
// v3: LDS subband exchange. Load/compute identical to v1 (222 us), but instead of
// each thread storing all 4 subbands (4 interleaved write streams per wave, 1 KiB
// bursts rotating across regions 16 MiB apart), the block parks outputs in LDS and
// wave w stores ONLY subband w: per-wave write streams 4 -> 1, bursts 1 KiB -> 4 KiB
// contiguous, and loads/stores are phase-separated by the barrier.
//   LDS: 4 subbands x 256 threads x 16 B = 16 KiB/block; write stride 16 B/lane and
//   read stride 16 B/lane are both bank-conflict-free. Occupancy limit stays the
//   32-wave cap (8 blocks/CU), not LDS (10 blocks/CU).
// Values are bitwise-identical to v1 (same arithmetic, just routed through LDS).
//
// (R3 resubmit: previous bench attempt died to "MI355X container failed twice" —
//  infra, no kernel verdict. Kernel unchanged.)

typedef float v4f __attribute__((ext_vector_type(4)));

__global__ __launch_bounds__(256) void dwt_haar_fwd(const float* __restrict__ in,
                                                    float* __restrict__ out) {
    __shared__ v4f lds[4][256];   // [subband][thread]

    const int tid = threadIdx.x;
    const int idx = blockIdx.x * 256 + tid;   // 0 .. 2,097,152
    const int w4  = idx & 31;           // group of 4 output cols (32 per 128-wide row)
    const int t   = idx >> 5;
    const int h2  = t & 127;            // output row
    const int pl  = t >> 7;             // input plane 0..511 (uniform per block: 8 t-values
                                        // per block never cross a 128-row plane boundary)

    const float* rbase = in + pl * 65536 + (h2 << 1) * 256 + (w4 << 3);
    const v4f* p0 = (const v4f*)rbase;           // row 2h2
    const v4f* p1 = (const v4f*)(rbase + 256);   // row 2h2+1
    const v4f r0a = __builtin_nontemporal_load(p0);     // a0 c0 a1 c1
    const v4f r0b = __builtin_nontemporal_load(p0 + 1); // a2 c2 a3 c3
    const v4f r1a = __builtin_nontemporal_load(p1);     // b0 d0 b1 d1
    const v4f r1b = __builtin_nontemporal_load(p1 + 1); // b2 d2 b3 d3

    // sums/diffs: s_e=a+b, s_o=c+d, d_e=a-b, d_o=c-d for 4 output columns
    const v4f s0 = r0a + r1a;   // se0 so0 se1 so1
    const v4f s1 = r0b + r1b;   // se2 so2 se3 so3
    const v4f d0 = r0a - r1a;   // de0 do0 de1 do1
    const v4f d1 = r0b - r1b;   // de2 do2 de3 do3

    lds[0][tid] = v4f{  0.5f * (s0.x + s0.y),  0.5f * (s0.z + s0.w),  0.5f * (s1.x + s1.y),  0.5f * (s1.z + s1.w) }; // LL
    lds[1][tid] = v4f{  0.5f * (s0.y - s0.x),  0.5f * (s0.w - s0.z),  0.5f * (s1.y - s1.x),  0.5f * (s1.w - s1.z) }; // HL
    lds[2][tid] = v4f{ -0.5f * (d0.x + d0.y), -0.5f * (d0.z + d0.w), -0.5f * (d1.x + d1.y), -0.5f * (d1.z + d1.w) }; // LH
    lds[3][tid] = v4f{  0.5f * (d0.x - d0.y),  0.5f * (d0.z - d0.w),  0.5f * (d1.x - d1.y),  0.5f * (d1.z - d1.w) }; // HH

    __syncthreads();

    // wave w stores subband w for the whole block: thread t' = j*64+ln produced
    // output offset t'*4 floats within this block's 4 KiB (8 rows x 512 B) region,
    // since (t'>>5)*128 + (t'&31)*4 == 4*t'.
    const int wv  = tid >> 6;           // wave id == subband id
    const int ln  = tid & 63;
    const int b   = pl >> 8;            // batch (uniform per block)
    const int pcd = pl & 255;           // c*16+d (uniform per block)
    const int h2b = (blockIdx.x * 8) & 127;   // block's first output row

    float* obase = out + (size_t)(b * 1024 + wv * 256 + pcd) * 16384 + (h2b << 7) + (ln << 2);
    #pragma unroll
    for (int j = 0; j < 4; ++j) {
        // per instruction: 64 lanes x 16 B = 1 KiB contiguous; 4 instructions = 4 KiB run
        __builtin_nontemporal_store(lds[wv][j * 64 + ln], (v4f*)(obase + j * 256));
    }
}

extern "C" void kernel_launch(void* const* d_in, const int* in_sizes, int n_in,
                              void* d_out, int out_size, void* d_ws, size_t ws_size,
                              hipStream_t stream) {
    const float* x = (const float*)d_in[0];
    float* out = (float*)d_out;
    // total threads = 512 planes * 128 rows * 32 col-quads = 2,097,152
    dwt_haar_fwd<<<8192, 256, 0, stream>>>(x, out);
}

// Round 5
// 222.814 us; speedup vs baseline: 1.0035x; 1.0035x over previous
//
#include <hip/hip_runtime.h>

// Haar DWT, mode=0 (no pad).
// in : (2,16,16,256,256) f32  -> plane pl = b*256 + pcd in [0,512), each plane 256x256
// out: (2,64,16,128,128) f32  -> flat (b*1024 + s*256 + pcd)*16384 + h2*128 + w2
//
// Per 2x2 quad (a=ev/ev, b=od/ev, c=ev/od, d=od/od), all *0.5:
//   LL = a+b+c+d ; HL = -a-b+c+d ; LH = -a+b-c+d ; HH = a-b-c+d
//
// Thread layout: idx = (plane[9b], h2[7b], w4[5b]); w4 indexes groups of 4 output cols.
//   loads : 2x 16B per input row (rows 2h2, 2h2+1), nontemporal (input is cold DRAM;
//           don't pollute L2). 1 KiB contiguous per instruction per half-wave.
//   stores: 1x 16B per subband, PLAIN (not nontemporal) — v4 experiment:
//           output is 128 MiB < 256 MiB Infinity Cache; plain stores can complete
//           at the L3 coherence point instead of draining to DRAM before the
//           kernel's final vmcnt(0), while nt stores force the DRAM round-trip.
//
// History: v1 per-thread 4-subband stores, all-nt = 222-223 us (x3 runs).
//          v2 2 units/thread (+64 MiB streams)  = 230 us  — MLP theory dead.
//          v3 LDS subband exchange (1 stream/wave, 4 KiB runs) = 223.6 us — stream-
//             fragmentation theory dead.
//          v4 = v1 with plain stores (this file) — L3 write-absorption test.

typedef float v4f __attribute__((ext_vector_type(4)));  // native vector: OK for nontemporal builtins

__global__ __launch_bounds__(256) void dwt_haar_fwd(const float* __restrict__ in,
                                                    float* __restrict__ out) {
    const int idx = blockIdx.x * 256 + threadIdx.x;   // 0 .. 2,097,152
    const int w4  = idx & 31;           // group of 4 output cols (32 per 128-wide row)
    const int t   = idx >> 5;
    const int h2  = t & 127;            // output row
    const int pl  = t >> 7;             // input plane 0..511
    const int b   = pl >> 8;            // batch
    const int pcd = pl & 255;           // c*16+d

    const float* rbase = in + pl * 65536 + (h2 << 1) * 256 + (w4 << 3);
    const v4f* p0 = (const v4f*)rbase;           // row 2h2
    const v4f* p1 = (const v4f*)(rbase + 256);   // row 2h2+1
    const v4f r0a = __builtin_nontemporal_load(p0);     // a0 c0 a1 c1
    const v4f r0b = __builtin_nontemporal_load(p0 + 1); // a2 c2 a3 c3
    const v4f r1a = __builtin_nontemporal_load(p1);     // b0 d0 b1 d1
    const v4f r1b = __builtin_nontemporal_load(p1 + 1); // b2 d2 b3 d3

    // sums/diffs: s_e=a+b, s_o=c+d, d_e=a-b, d_o=c-d for 4 output columns
    const v4f s0 = r0a + r1a;   // se0 so0 se1 so1
    const v4f s1 = r0b + r1b;   // se2 so2 se3 so3
    const v4f d0 = r0a - r1a;   // de0 do0 de1 do1
    const v4f d1 = r0b - r1b;   // de2 do2 de3 do3

    const v4f LL = {  0.5f * (s0.x + s0.y),  0.5f * (s0.z + s0.w),  0.5f * (s1.x + s1.y),  0.5f * (s1.z + s1.w) };
    const v4f HL = {  0.5f * (s0.y - s0.x),  0.5f * (s0.w - s0.z),  0.5f * (s1.y - s1.x),  0.5f * (s1.w - s1.z) };
    const v4f LH = { -0.5f * (d0.x + d0.y), -0.5f * (d0.z + d0.w), -0.5f * (d1.x + d1.y), -0.5f * (d1.z + d1.w) };
    const v4f HH = {  0.5f * (d0.x - d0.y),  0.5f * (d0.z - d0.w),  0.5f * (d1.x - d1.y),  0.5f * (d1.z - d1.w) };

    float* obase = out + (size_t)(b * 1024 + pcd) * 16384 + (h2 << 7) + (w4 << 2);
    *(v4f*)(obase           ) = LL;   // s=0
    *(v4f*)(obase + 4194304 ) = HL;   // s=1: +256*16384
    *(v4f*)(obase + 8388608 ) = LH;   // s=2
    *(v4f*)(obase + 12582912) = HH;   // s=3
}

extern "C" void kernel_launch(void* const* d_in, const int* in_sizes, int n_in,
                              void* d_out, int out_size, void* d_ws, size_t ws_size,
                              hipStream_t stream) {
    const float* x = (const float*)d_in[0];
    float* out = (float*)d_out;
    // total threads = 512 planes * 128 rows * 32 col-quads = 2,097,152
    dwt_haar_fwd<<<8192, 256, 0, stream>>>(x, out);
}